// Round 8
// baseline (157740.979 us; speedup 1.0000x reference)
//
#include <hip/hip_runtime.h>
#include <math.h>

#define T_STEPS 65536
#define HID     512
#define NWG     32     // 32 WGs x 256 thr = 8192 threads, 128 waves
#define WGSIZE  256

typedef float f2v __attribute__((ext_vector_type(2)));

// Decomposition: WG owns 16 h-indices [wg*16, wg*16+16) -> 64 gate-rows.
//   wave wid (0..3): h-indices wg*16 + wid*4 + jloc, jloc in [0,4)
//   lane = g*16 + jloc*4 + gate   (gate: 0=i 1=f 2=g 3=o; g = k-group, 128 k each)
//   Each lane holds 128 fp32 of W_hh and 128 of W_ih in VGPRs (its row x k-slice).
// Exchange (R2-proven primitive): hbuf[2][512] packed 8B words
//   (hi32 = tag = t+1, lo32 = f32 h bits), relaxed agent-scope atomics.
//   Each thread polls exactly its 2 words (16B) - minimal LIC contention.
// One __syncthreads per step (double-buffered LDS).

__global__ __launch_bounds__(WGSIZE, 1)
void lstm_32wg(const float* __restrict__ x,      // [T,512]
               const float* __restrict__ Wih,    // [2048,512]
               const float* __restrict__ Whh,    // [2048,512]
               const float* __restrict__ bih,    // [2048]
               const float* __restrict__ bhh,    // [2048]
               float* __restrict__ out,          // [512]
               unsigned long long* hbuf)         // [2][512] tagged pairs
{
  const int wg   = blockIdx.x;
  const int tid  = threadIdx.x;
  const int wid  = tid >> 6;
  const int lane = tid & 63;
  const int gate = lane & 3;          // 0=i 1=f 2=g 3=o
  const int jloc = (lane >> 2) & 3;
  const int g    = lane >> 4;         // k-group: k in [g*128, g*128+128)
  const int kb   = g << 7;
  const int hidx = wg * 16 + wid * 4 + jloc;
  const int row  = gate * HID + hidx;

  __shared__ __align__(16) float hl[2][512];
  __shared__ __align__(16) float xl[2][512];

  // ---- load weights into registers (rotation (i+g)&31 baked into order) ----
  float whh[128], wih[128];
#pragma unroll
  for (int i = 0; i < 32; ++i) {
    const int kk = kb + (((i + g) & 31) << 2);
    float4 a = *reinterpret_cast<const float4*>(Whh + (size_t)row * 512 + kk);
    float4 b = *reinterpret_cast<const float4*>(Wih + (size_t)row * 512 + kk);
    whh[4*i+0] = a.x; whh[4*i+1] = a.y; whh[4*i+2] = a.z; whh[4*i+3] = a.w;
    wih[4*i+0] = b.x; wih[4*i+1] = b.y; wih[4*i+2] = b.z; wih[4*i+3] = b.w;
  }
  const float bias = bih[row] + bhh[row];

  // ---- stage x_0 (each thread: 2 floats) ----
  {
    f2v v = *(reinterpret_cast<const f2v*>(x) + tid);
    *reinterpret_cast<f2v*>(&xl[0][tid * 2]) = v;
  }
  __syncthreads();

  // 128 MAC from LDS; 16-lane broadcast per address, g-groups on disjoint
  // banks via (i+g)&31 rotation -> conflict-free. 4 accumulators (dep 32).
  auto dot_lds = [&](const float* lds, const float* w) -> float {
    float a0 = 0.f, a1 = 0.f, a2 = 0.f, a3 = 0.f;
#pragma unroll
    for (int i = 0; i < 32; ++i) {
      const int kk = kb + (((i + g) & 31) << 2);
      float4 v = *reinterpret_cast<const float4*>(lds + kk);
      a0 = fmaf(w[4*i+0], v.x, a0);
      a1 = fmaf(w[4*i+1], v.y, a1);
      a2 = fmaf(w[4*i+2], v.z, a2);
      a3 = fmaf(w[4*i+3], v.w, a3);
    }
    return (a0 + a1) + (a2 + a3);
  };

  float xacc = dot_lds(xl[0], wih);   // x-projection partial for t=0
  float c    = 0.f;

#pragma unroll 1
  for (int t = 0; t < T_STEPS; ++t) {
    // ---- prefetch x_{t+1} (8B/thread, nontemporal) ----
    f2v xv;
    const bool do_x = (t + 1 < T_STEPS);
    if (do_x) {
      const f2v* xp = reinterpret_cast<const f2v*>(x + (size_t)(t + 1) * 512) + tid;
      xv = __builtin_nontemporal_load(xp);
    }

    // ---- poll my 2 tagged words of h_{t-1} (16B, R2-proven pattern) ----
    if (t > 0) {
      const unsigned long long* src = hbuf + (((t - 1) & 1) << 9) + (tid << 1);
      const unsigned exp = (unsigned)t;
      unsigned long long p0, p1;
      while (true) {
        p0 = __hip_atomic_load(src + 0, __ATOMIC_RELAXED, __HIP_MEMORY_SCOPE_AGENT);
        p1 = __hip_atomic_load(src + 1, __ATOMIC_RELAXED, __HIP_MEMORY_SCOPE_AGENT);
        if ((unsigned)(p0 >> 32) == exp && (unsigned)(p1 >> 32) == exp) break;
      }
      f2v hv = { __uint_as_float((unsigned)p0), __uint_as_float((unsigned)p1) };
      *reinterpret_cast<f2v*>(&hl[t & 1][tid * 2]) = hv;
    }
    if (do_x) *reinterpret_cast<f2v*>(&xl[(t + 1) & 1][tid * 2]) = xv;
    __syncthreads();   // single barrier per step (LDS double-buffered)

    // ---- gate pre-activation: xacc + h-dot; reduce across 4 k-groups ----
    float acc = xacc;
    if (t > 0) acc += dot_lds(hl[t & 1], whh);
    acc += __shfl_xor(acc, 16);
    acc += __shfl_xor(acc, 32);
    acc += bias;

    // ---- nonlinearity: sigmoid for i,f,o; tanh (=2*sig(2x)-1) for g ----
    const bool isg = (gate == 2);
    float xs = isg ? 2.f * acc : acc;
    float s  = 1.f / (1.f + expf(-xs));
    float v  = isg ? (2.f * s - 1.f) : s;

    // ---- gather i,f,g,o within my (g, jloc) quad ----
    const int base = lane & ~3;
    float iv = __shfl(v, base + 0);
    float fv = __shfl(v, base + 1);
    float gv = __shfl(v, base + 2);
    float ov = __shfl(v, base + 3);

    c = fv * c + iv * gv;
    float e2 = expf(-2.f * c);
    float th = 2.f / (1.f + e2) - 1.f;
    float hn = ov * th;

    // ---- post tagged h_t (lanes 0,4,8,12: g==0 && gate==0) ----
    if ((lane & 0x33) == 0 || (lane < 16 && gate == 0)) { /* simplified below */ }
    if (lane < 16 && gate == 0) {
      unsigned long long pk =
          ((unsigned long long)(unsigned)(t + 1) << 32) | (unsigned)__float_as_uint(hn);
      __hip_atomic_store(hbuf + ((t & 1) << 9) + wg * 16 + wid * 4 + jloc, pk,
                         __ATOMIC_RELAXED, __HIP_MEMORY_SCOPE_AGENT);
    }

    // ---- off critical path: x-projection for t+1 ----
    if (do_x) xacc = dot_lds(xl[(t + 1) & 1], wih);
  }

  // ---- softmax(h_{T-1}) by wg 0, wave 0 ----
  if (wg == 0 && tid < 64) {
    const unsigned long long* src = hbuf + (((T_STEPS - 1) & 1) << 9) + lane * 8;
    unsigned long long p[8];
    bool ok;
    do {
#pragma unroll
      for (int j = 0; j < 8; ++j)
        p[j] = __hip_atomic_load(src + j, __ATOMIC_RELAXED, __HIP_MEMORY_SCOPE_AGENT);
      ok = true;
#pragma unroll
      for (int j = 0; j < 8; ++j) ok &= ((unsigned)(p[j] >> 32) == (unsigned)T_STEPS);
    } while (!__all(ok));

    float hv[8];
#pragma unroll
    for (int j = 0; j < 8; ++j) hv[j] = __uint_as_float((unsigned)p[j]);
    float mx = hv[0];
#pragma unroll
    for (int j = 1; j < 8; ++j) mx = fmaxf(mx, hv[j]);
    mx = fmaxf(mx, __shfl_xor(mx, 1));
    mx = fmaxf(mx, __shfl_xor(mx, 2));
    mx = fmaxf(mx, __shfl_xor(mx, 4));
    mx = fmaxf(mx, __shfl_xor(mx, 8));
    mx = fmaxf(mx, __shfl_xor(mx, 16));
    mx = fmaxf(mx, __shfl_xor(mx, 32));
    float ex[8], sum = 0.f;
#pragma unroll
    for (int j = 0; j < 8; ++j) { ex[j] = expf(hv[j] - mx); sum += ex[j]; }
    sum += __shfl_xor(sum, 1);
    sum += __shfl_xor(sum, 2);
    sum += __shfl_xor(sum, 4);
    sum += __shfl_xor(sum, 8);
    sum += __shfl_xor(sum, 16);
    sum += __shfl_xor(sum, 32);
    float inv = 1.f / sum;
#pragma unroll
    for (int j = 0; j < 8; ++j) out[lane * 8 + j] = ex[j] * inv;
  }
}

extern "C" void kernel_launch(void* const* d_in, const int* in_sizes, int n_in,
                              void* d_out, int out_size, void* d_ws, size_t ws_size,
                              hipStream_t stream) {
  const float* x   = (const float*)d_in[0];
  const float* Wih = (const float*)d_in[1];
  const float* Whh = (const float*)d_in[2];
  const float* bih = (const float*)d_in[3];
  const float* bhh = (const float*)d_in[4];
  float* out = (float*)d_out;
  unsigned long long* hbuf = (unsigned long long*)d_ws;   // 2*512*8B = 8 KB

  (void)hipMemsetAsync(d_ws, 0, 8192, stream);  // zero tags each launch (capture-safe)
  lstm_32wg<<<NWG, WGSIZE, 0, stream>>>(x, Wih, Whh, bih, bhh, out, hbuf);
}

// Round 9
// 100560.486 us; speedup vs baseline: 1.5686x; 1.5686x over previous
//
#include <hip/hip_runtime.h>
#include <math.h>

#define T_STEPS 65536
#define HID     512
#define NWG     64
#define WGSIZE  256

// R2 structure (best measured: 1.63us/step) + weight pinning.
//
// Layout per workgroup (256 thr = 4 waves):
//   WG owns 8 h-indices: [wg*8, wg*8+8).
//   Wave wid owns 2 h-indices: wg*8 + wid*2 + {0,1}.
//   Within a wave: lane = r + 8*g, r in [0,8) = row-in-wave, g in [0,8) = k-group.
//     row r -> (jloc = r&1, gate = r>>1)  (gate order i,f,g,o as in PyTorch)
//   Each lane holds 64 fp32 of W_hh and 64 of W_ih for its (row, k-slice).
//
// KEY FIX (R9): asm-pin the weight arrays after loading. Without it the
// compiler rematerializes the (const __restrict__) global loads inside the
// step loop -> every CU re-streams 128KB/step from L2 (~0.8us hidden on the
// critical path; VGPR_Count was 100 < the 128 declared weight floats).
//
// Cross-WG h exchange (proven primitive): hbuf[2][512] packed 8B words
// (hi32 = tag = t+1, lo32 = f32 h bits), relaxed agent-scope atomic store,
// polled with relaxed agent-scope atomic loads (16B/thread).

__global__ __launch_bounds__(WGSIZE, 1)
void lstm_persistent(const float* __restrict__ x,      // [T,512]
                     const float* __restrict__ Wih,    // [2048,512]
                     const float* __restrict__ Whh,    // [2048,512]
                     const float* __restrict__ bih,    // [2048]
                     const float* __restrict__ bhh,    // [2048]
                     float* __restrict__ out,          // [512]
                     unsigned long long* hbuf)         // [2][512] tagged pairs
{
  const int wg   = blockIdx.x;
  const int tid  = threadIdx.x;
  const int wid  = tid >> 6;
  const int lane = tid & 63;
  const int r    = lane & 7;
  const int g    = lane >> 3;
  const int k0   = g << 6;            // 64-float k-slice start
  const int jloc = r & 1;
  const int gate = r >> 1;            // 0=i 1=f 2=g 3=o
  const int hidx = wg * 8 + wid * 2 + jloc;
  const int row  = gate * HID + hidx;

  __shared__ __align__(16) float hlds[512];
  __shared__ __align__(16) float xlds[512];

  // ---- load weights into registers (static indices only) ----
  float whh[64], wih[64];
#pragma unroll
  for (int i = 0; i < 16; ++i) {
    const int kk = k0 + (((i + g) & 15) << 2);
    float4 a = *reinterpret_cast<const float4*>(Whh + (size_t)row * 512 + kk);
    float4 b = *reinterpret_cast<const float4*>(Wih + (size_t)row * 512 + kk);
    whh[4*i+0] = a.x; whh[4*i+1] = a.y; whh[4*i+2] = a.z; whh[4*i+3] = a.w;
    wih[4*i+0] = b.x; wih[4*i+1] = b.y; wih[4*i+2] = b.z; wih[4*i+3] = b.w;
  }
  float bias = bih[row] + bhh[row];

  // ---- PIN weights in VGPRs: make values opaque so the compiler cannot
  // rematerialize the global loads inside the step loop ----
#pragma unroll
  for (int i = 0; i < 64; ++i) {
    asm volatile("" : "+v"(whh[i]));
    asm volatile("" : "+v"(wih[i]));
  }
  asm volatile("" : "+v"(bias));

  // ---- stage x_0 ----
  if (tid < 128) {
    float4 v = reinterpret_cast<const float4*>(x)[tid];
    *reinterpret_cast<float4*>(xlds + tid * 4) = v;
  }
  __syncthreads();

  auto dot_lds = [&](const float* lds, const float* w) -> float {
    float acc = 0.f;
#pragma unroll
    for (int i = 0; i < 16; ++i) {
      const int kk = k0 + (((i + g) & 15) << 2);
      float4 v = *reinterpret_cast<const float4*>(lds + kk);
      acc = fmaf(w[4*i+0], v.x, acc);
      acc = fmaf(w[4*i+1], v.y, acc);
      acc = fmaf(w[4*i+2], v.z, acc);
      acc = fmaf(w[4*i+3], v.w, acc);
    }
    return acc;
  };

  float xacc = dot_lds(xlds, wih);   // x-projection partial for t=0
  float c    = 0.f;

#pragma unroll 1
  for (int t = 0; t < T_STEPS; ++t) {
    // ---- stage: poll tagged h_{t-1} (all threads, 2 words each) + x_{t+1} ----
    float4 xv;
    const bool do_x = (tid < 128) && (t + 1 < T_STEPS);
    if (do_x) xv = reinterpret_cast<const float4*>(x + (size_t)(t + 1) * 512)[tid];

    if (t > 0) {
      const unsigned long long* src = hbuf + (((t - 1) & 1) << 9) + (tid << 1);
      const unsigned exp = (unsigned)t;
      unsigned long long p0, p1;
      while (true) {
        p0 = __hip_atomic_load(src + 0, __ATOMIC_RELAXED, __HIP_MEMORY_SCOPE_AGENT);
        p1 = __hip_atomic_load(src + 1, __ATOMIC_RELAXED, __HIP_MEMORY_SCOPE_AGENT);
        if ((unsigned)(p0 >> 32) == exp && (unsigned)(p1 >> 32) == exp) break;
      }
      hlds[(tid << 1) + 0] = __uint_as_float((unsigned)p0);
      hlds[(tid << 1) + 1] = __uint_as_float((unsigned)p1);
    }
    if (do_x) *reinterpret_cast<float4*>(xlds + tid * 4) = xv;
    __syncthreads();  // staging complete

    // ---- gate pre-activation: xacc (precomputed) + h-dot, reduce over 8 k-groups ----
    float acc = xacc;
    if (t > 0) acc += dot_lds(hlds, whh);
    acc += __shfl_xor(acc, 8);
    acc += __shfl_xor(acc, 16);
    acc += __shfl_xor(acc, 32);
    acc += bias;

    // ---- nonlinearity: sigmoid for i,f,o; tanh (=2*sig(2x)-1) for g ----
    const bool isg = (gate == 2);
    float xs = isg ? 2.f * acc : acc;
    float s  = 1.f / (1.f + expf(-xs));
    float v  = isg ? (2.f * s - 1.f) : s;

    // ---- gather i,f,g,o for my jloc via in-wave shuffles ----
    float iv = __shfl(v, jloc + 0);
    float fv = __shfl(v, jloc + 2);
    float gv = __shfl(v, jloc + 4);
    float ov = __shfl(v, jloc + 6);

    c = fv * c + iv * gv;
    float e2 = expf(-2.f * c);
    float th = 2.f / (1.f + e2) - 1.f;
    float hn = ov * th;

    // ---- post tagged h_t (lanes 0,1 of every wave): single 8B fire-and-forget ----
    if (lane < 2) {
      unsigned long long pk =
          ((unsigned long long)(unsigned)(t + 1) << 32) | (unsigned)__float_as_uint(hn);
      __hip_atomic_store(hbuf + ((t & 1) << 9) + wg * 8 + wid * 2 + lane, pk,
                         __ATOMIC_RELAXED, __HIP_MEMORY_SCOPE_AGENT);
    }

    // ---- overlap: x-projection partial for step t+1 (hides peers' latency) ----
    if (t + 1 < T_STEPS) xacc = dot_lds(xlds, wih);
    __syncthreads();  // everyone done with hlds/xlds before next staging
  }

  // ---- softmax(h_{T-1}) by wg 0, wave 0 ----
  if (wg == 0 && wid == 0) {
    const unsigned long long* src = hbuf + (((T_STEPS - 1) & 1) << 9);
    float hv[8];
    {
      unsigned long long p[8];
      while (true) {
        bool ok = true;
#pragma unroll
        for (int m2 = 0; m2 < 8; ++m2) {
          p[m2] = __hip_atomic_load(src + lane * 8 + m2,
                                    __ATOMIC_RELAXED, __HIP_MEMORY_SCOPE_AGENT);
          ok &= ((unsigned)(p[m2] >> 32) == (unsigned)T_STEPS);
        }
        if (__all(ok)) break;
      }
#pragma unroll
      for (int m2 = 0; m2 < 8; ++m2) hv[m2] = __uint_as_float((unsigned)p[m2]);
    }
    float mx = hv[0];
#pragma unroll
    for (int m2 = 1; m2 < 8; ++m2) mx = fmaxf(mx, hv[m2]);
    mx = fmaxf(mx, __shfl_xor(mx, 1));
    mx = fmaxf(mx, __shfl_xor(mx, 2));
    mx = fmaxf(mx, __shfl_xor(mx, 4));
    mx = fmaxf(mx, __shfl_xor(mx, 8));
    mx = fmaxf(mx, __shfl_xor(mx, 16));
    mx = fmaxf(mx, __shfl_xor(mx, 32));
    float ex[8], sum = 0.f;
#pragma unroll
    for (int m2 = 0; m2 < 8; ++m2) { ex[m2] = expf(hv[m2] - mx); sum += ex[m2]; }
    sum += __shfl_xor(sum, 1);
    sum += __shfl_xor(sum, 2);
    sum += __shfl_xor(sum, 4);
    sum += __shfl_xor(sum, 8);
    sum += __shfl_xor(sum, 16);
    sum += __shfl_xor(sum, 32);
    float inv = 1.f / sum;
#pragma unroll
    for (int m2 = 0; m2 < 8; ++m2) out[lane * 8 + m2] = ex[m2] * inv;
  }
}

extern "C" void kernel_launch(void* const* d_in, const int* in_sizes, int n_in,
                              void* d_out, int out_size, void* d_ws, size_t ws_size,
                              hipStream_t stream) {
  const float* x   = (const float*)d_in[0];
  const float* Wih = (const float*)d_in[1];
  const float* Whh = (const float*)d_in[2];
  const float* bih = (const float*)d_in[3];
  const float* bhh = (const float*)d_in[4];
  float* out = (float*)d_out;
  unsigned long long* hbuf = (unsigned long long*)d_ws;  // 2 x 512 x 8B = 8 KB

  (void)hipMemsetAsync(d_ws, 0, 8192, stream);  // zero tags each launch (capture-safe)
  lstm_persistent<<<NWG, WGSIZE, 0, stream>>>(x, Wih, Whh, bih, bhh, out, hbuf);
}